// Round 8
// baseline (208.294 us; speedup 1.0000x reference)
//
#include <hip/hip_runtime.h>
#include <hip/hip_bf16.h>

typedef __bf16 bf16;
typedef __bf16 bf16x8 __attribute__((ext_vector_type(8)));
typedef __bf16 bf16x4 __attribute__((ext_vector_type(4)));
typedef float f32x4 __attribute__((ext_vector_type(4)));
typedef int int4v __attribute__((ext_vector_type(4)));
typedef int int2v __attribute__((ext_vector_type(2)));

#define DEV static __device__ __forceinline__

DEV void gload16(const void* g, void* l) {
    __builtin_amdgcn_global_load_lds(
        (const __attribute__((address_space(1))) void*)g,
        (__attribute__((address_space(3))) void*)l, 16, 0, 0);
}

DEV f32x4 mfma16(bf16x8 a, bf16x8 b, f32x4 c) {
    return __builtin_amdgcn_mfma_f32_16x16x32_bf16(a, b, c, 0, 0, 0);
}

DEV int cvtpk(float lo, float hi) {
    int r;
    asm("v_cvt_pk_bf16_f32 %0, %1, %2" : "=v"(r) : "v"(lo), "v"(hi));
    return r;
}

DEV float rexp2(float x) {   // raw v_exp_f32 (no denormal guard)
    float r;
    asm("v_exp_f32 %0, %1" : "=v"(r) : "v"(x));
    return r;
}

// ---------------------------------------------------------------
// x [B][512][4096] -> t [B*4096][512] (fp32), tiled transpose
__global__ __launch_bounds__(256)
void k_transpose_x(const float* __restrict__ x, float* __restrict__ t) {
    __shared__ float tile[32][33];
    int bid = blockIdx.x;
    int nt = bid & 127, ct = (bid >> 7) & 15, b = bid >> 11;
    int n0 = nt * 32, c0 = ct * 32;
    int tid = threadIdx.x;
    const float* xb = x + (size_t)b * 512 * 4096;
    int nl = tid & 31, cl = tid >> 5;
#pragma unroll
    for (int i = 0; i < 4; i++) {
        int c = cl + i * 8;
        tile[c][nl] = xb[(size_t)(c0 + c) * 4096 + n0 + nl];
    }
    __syncthreads();
    float* tb = t + (size_t)b * 4096 * 512;
    int cl2 = tid & 31, nl2 = tid >> 5;
#pragma unroll
    for (int i = 0; i < 4; i++) {
        int n = nl2 + i * 8;
        tb[(size_t)(n0 + n) * 512 + c0 + cl2] = tile[cl2][n];
    }
}

// ---------------------------------------------------------------
// y [B][512][4096] = transpose(t + f2o) + x   (final residual fused)
__global__ __launch_bounds__(256)
void k_out3(const float* __restrict__ t, const bf16* __restrict__ f2o,
            const float* __restrict__ x, float* __restrict__ y) {
    __shared__ float tile[32][33];
    int bid = blockIdx.x;
    int nt = bid & 127, ct = (bid >> 7) & 15, b = bid >> 11;
    int n0 = nt * 32, c0 = ct * 32;
    int tid = threadIdx.x;
#pragma unroll
    for (int i = 0; i < 4; i++) {
        int nl = (tid >> 5) + i * 8;
        size_t idx = (size_t)(b * 4096 + n0 + nl) * 512 + c0 + (tid & 31);
        tile[tid & 31][nl] = t[idx] + (float)f2o[idx];
    }
    __syncthreads();
    const float* xb = x + ((size_t)b * 512 + c0) * 4096;
    float* yb = y + ((size_t)b * 512 + c0) * 4096;
#pragma unroll
    for (int i = 0; i < 4; i++) {
        int cl = (tid >> 5) + i * 8;
        int nl = tid & 31;
        size_t off = (size_t)cl * 4096 + n0 + nl;
        yb[off] = tile[cl][nl] + xb[off];
    }
}

// ---------------------------------------------------------------
// LayerNorm: t fp32 -> h bf16. One wave per row.
__global__ __launch_bounds__(256)
void k_ln(const float* __restrict__ t, const float* __restrict__ gg,
          const float* __restrict__ bb, bf16* __restrict__ h) {
    int lane = threadIdx.x & 63;
    int row = blockIdx.x * 4 + (threadIdx.x >> 6);
    const float* tr = t + (size_t)row * 512;
    f32x4 v0 = *(const f32x4*)(tr + lane * 4);
    f32x4 v1 = *(const f32x4*)(tr + 256 + lane * 4);
    float s = v0[0] + v0[1] + v0[2] + v0[3] + v1[0] + v1[1] + v1[2] + v1[3];
#pragma unroll
    for (int m = 1; m < 64; m <<= 1) s += __shfl_xor(s, m);
    float mu = s * (1.0f / 512.0f);
    float vs = 0.f;
#pragma unroll
    for (int j = 0; j < 4; j++) {
        float d0 = v0[j] - mu, d1 = v1[j] - mu;
        vs += d0 * d0 + d1 * d1;
    }
#pragma unroll
    for (int m = 1; m < 64; m <<= 1) vs += __shfl_xor(vs, m);
    float rs = rsqrtf(vs * (1.0f / 512.0f) + 1e-5f);
    f32x4 g0 = *(const f32x4*)(gg + lane * 4);
    f32x4 g1 = *(const f32x4*)(gg + 256 + lane * 4);
    f32x4 b0 = *(const f32x4*)(bb + lane * 4);
    f32x4 b1 = *(const f32x4*)(bb + 256 + lane * 4);
    bf16x4 o0, o1;
#pragma unroll
    for (int j = 0; j < 4; j++) {
        o0[j] = (bf16)((v0[j] - mu) * rs * g0[j] + b0[j]);
        o1[j] = (bf16)((v1[j] - mu) * rs * g1[j] + b1[j]);
    }
    *(bf16x4*)(h + (size_t)row * 512 + lane * 4) = o0;
    *(bf16x4*)(h + (size_t)row * 512 + 256 + lane * 4) = o1;
}

// ---------------------------------------------------------------
// Fused residual + LayerNorm: t = t + r(bf16); h = LN(t). In-place t.
__global__ __launch_bounds__(256)
void k_lnr(float* __restrict__ t, const bf16* __restrict__ r,
           const float* __restrict__ gg, const float* __restrict__ bb,
           bf16* __restrict__ h) {
    int lane = threadIdx.x & 63;
    int row = blockIdx.x * 4 + (threadIdx.x >> 6);
    float* tr = t + (size_t)row * 512;
    f32x4 v0 = *(const f32x4*)(tr + lane * 4);
    f32x4 v1 = *(const f32x4*)(tr + 256 + lane * 4);
    bf16x4 r0 = *(const bf16x4*)(r + (size_t)row * 512 + lane * 4);
    bf16x4 r1 = *(const bf16x4*)(r + (size_t)row * 512 + 256 + lane * 4);
#pragma unroll
    for (int j = 0; j < 4; j++) {
        v0[j] += (float)r0[j];
        v1[j] += (float)r1[j];
    }
    *(f32x4*)(tr + lane * 4) = v0;
    *(f32x4*)(tr + 256 + lane * 4) = v1;
    float s = v0[0] + v0[1] + v0[2] + v0[3] + v1[0] + v1[1] + v1[2] + v1[3];
#pragma unroll
    for (int m = 1; m < 64; m <<= 1) s += __shfl_xor(s, m);
    float mu = s * (1.0f / 512.0f);
    float vs = 0.f;
#pragma unroll
    for (int j = 0; j < 4; j++) {
        float d0 = v0[j] - mu, d1 = v1[j] - mu;
        vs += d0 * d0 + d1 * d1;
    }
#pragma unroll
    for (int m = 1; m < 64; m <<= 1) vs += __shfl_xor(vs, m);
    float rs = rsqrtf(vs * (1.0f / 512.0f) + 1e-5f);
    f32x4 g0 = *(const f32x4*)(gg + lane * 4);
    f32x4 g1 = *(const f32x4*)(gg + 256 + lane * 4);
    f32x4 b0 = *(const f32x4*)(bb + lane * 4);
    f32x4 b1 = *(const f32x4*)(bb + 256 + lane * 4);
    bf16x4 o0, o1;
#pragma unroll
    for (int j = 0; j < 4; j++) {
        o0[j] = (bf16)((v0[j] - mu) * rs * g0[j] + b0[j]);
        o1[j] = (bf16)((v1[j] - mu) * rs * g1[j] + b1[j]);
    }
    *(bf16x4*)(h + (size_t)row * 512 + lane * 4) = o0;
    *(bf16x4*)(h + (size_t)row * 512 + 256 + lane * 4) = o1;
}

// ---------------------------------------------------------------
// Weight prep: W [K][N] fp32 -> WT [N][K] bf16
__global__ __launch_bounds__(256)
void k_wt(const float* __restrict__ w, bf16* __restrict__ wt, int K, int N) {
    __shared__ float tile[32][33];
    int ntn = N >> 5;
    int kt = blockIdx.x / ntn, ntile = blockIdx.x % ntn;
    int k0 = kt * 32, n0 = ntile * 32;
    int tid = threadIdx.x;
    int nl = tid & 31, kl = tid >> 5;
#pragma unroll
    for (int i = 0; i < 4; i++) {
        int k = kl + i * 8;
        tile[k][nl] = w[(size_t)(k0 + k) * N + n0 + nl];
    }
    __syncthreads();
    int kl2 = tid & 31, nl2 = tid >> 5;
#pragma unroll
    for (int i = 0; i < 4; i++) {
        int n = nl2 + i * 8;
        wt[(size_t)(n0 + n) * K + k0 + kl2] = (bf16)tile[kl2][n];
    }
}

// ---------------------------------------------------------------
// GEMM: out[M][N](bf16) = A[M][K](bf16) @ BT[N][K]^T + bias.
// Template: MODE 0 plain / 1 relu / 2 qkv (V-slice transposed into vt);
// BN = 128 or 64 (64 doubles the grid for small-N GEMMs -> occupancy).
// Counted-vmcnt 2-barrier pipeline; LDS-bounce coalesced epilogue.
template <int MODE, int BN>
__global__ __launch_bounds__(256, 2)
void k_gemm(const bf16* __restrict__ A, const bf16* __restrict__ BT,
            const float* __restrict__ bias, bf16* __restrict__ outb,
            bf16* __restrict__ vtout, int M, int N, int K) {
    __shared__ char smem[65536];   // A bufs @0, B bufs @32768 (16KB stride)
    constexpr int CG = BN / 32;    // col-groups per wave; also B stage passes
    int ntn = N / BN;
    int nwg = gridDim.x;
    int bid = blockIdx.x;
    int cpx = nwg >> 3;
    bid = (bid & 7) * cpx + (bid >> 3);       // XCD-aware swizzle
    int bm = bid / ntn, bn = bid % ntn;
    int m0 = bm * 128, n0 = bn * BN;
    int tid = threadIdx.x;
    int w = tid >> 6, l = tid & 63;
    int wm = w >> 1, wn = w & 1;
    int l15 = l & 15, lg = l >> 4;

    f32x4 acc[4][CG];
#pragma unroll
    for (int i = 0; i < 4; i++)
#pragma unroll
        for (int j = 0; j < CG; j++) acc[i][j] = (f32x4){0.f, 0.f, 0.f, 0.f};

    int srow = tid >> 3, sphys = tid & 7;
    int lrow_a = wm * 64 + l15;
    int lrow_b = wn * (BN / 2) + l15;

#define GEMM_STAGE(k0v, bb)                                                  \
    do {                                                                     \
        _Pragma("unroll") for (int s = 0; s < 4; s++) {                      \
            int row = s * 32 + srow;                                         \
            int k16 = sphys ^ (row & 7);                                     \
            gload16(A + (size_t)(m0 + row) * K + (k0v) + k16 * 8,            \
                    smem + (bb) * 16384 + s * 4096 + tid * 16);              \
        }                                                                    \
        _Pragma("unroll") for (int s = 0; s < CG; s++) {                     \
            int row = s * 32 + srow;                                         \
            int k16 = sphys ^ (row & 7);                                     \
            gload16(BT + (size_t)(n0 + row) * K + (k0v) + k16 * 8,           \
                    smem + 32768 + (bb) * 16384 + s * 4096 + tid * 16);      \
        }                                                                    \
    } while (0)

    int nk = K >> 6;
    GEMM_STAGE(0, 0);
    int cur = 0;
    for (int kt = 0; kt < nk; kt++) {
        if (kt + 1 < nk) {
            GEMM_STAGE((kt + 1) << 6, cur ^ 1);
            if constexpr (BN == 128)
                asm volatile("s_waitcnt vmcnt(8)" ::: "memory");
            else
                asm volatile("s_waitcnt vmcnt(6)" ::: "memory");
        } else {
            asm volatile("s_waitcnt vmcnt(0)" ::: "memory");
        }
        __builtin_amdgcn_s_barrier();
        __builtin_amdgcn_sched_barrier(0);
        const char* pA = smem + cur * 16384;
        const char* pB = smem + 32768 + cur * 16384;
#pragma unroll
        for (int ks = 0; ks < 2; ks++) {
            bf16x8 af[4], bfr[CG];
#pragma unroll
            for (int rg = 0; rg < 4; rg++) {
                int row = lrow_a + rg * 16;
                af[rg] = *(const bf16x8*)(pA + row * 128 +
                                          (((lg + ks * 4) ^ (row & 7)) << 4));
            }
#pragma unroll
            for (int cg = 0; cg < CG; cg++) {
                int row = lrow_b + cg * 16;
                bfr[cg] = *(const bf16x8*)(pB + row * 128 +
                                           (((lg + ks * 4) ^ (row & 7)) << 4));
            }
#pragma unroll
            for (int rg = 0; rg < 4; rg++)
#pragma unroll
                for (int cg = 0; cg < CG; cg++)
                    acc[rg][cg] = mfma16(af[rg], bfr[cg], acc[rg][cg]);
        }
        __builtin_amdgcn_s_barrier();
        cur ^= 1;
    }
#undef GEMM_STAGE

    if constexpr (MODE == 2) {
        if (n0 >= 1024) {
            // ---- V-slice: transposed epilogue into vt [bh][64][4096]
            char* vl = smem;        // col-major [128 col][136 row] bf16
#pragma unroll
            for (int cg = 0; cg < CG; cg++) {
                int col = wn * 64 + cg * 16 + l15;
                float bz = bias[n0 + col];
#pragma unroll
                for (int rg = 0; rg < 4; rg++) {
                    int rowb = wm * 64 + rg * 16 + lg * 4;
                    int2v qq = {cvtpk(acc[rg][cg][0] + bz, acc[rg][cg][1] + bz),
                                cvtpk(acc[rg][cg][2] + bz, acc[rg][cg][3] + bz)};
                    *(int2v*)(vl + col * 272 + rowb * 2) = qq;
                }
            }
            __syncthreads();
            int b = m0 >> 12, nrow0 = m0 & 4095;
            int dl = tid >> 3, c8 = tid & 7;
#pragma unroll
            for (int dd = 0; dd < 4; dd++) {
                int d = dd * 32 + dl;
                int ch = (n0 - 1024) + d;
                bf16* dst = vtout +
                    ((size_t)((b * 8 + (ch >> 6)) * 64 + (ch & 63))) * 4096 + nrow0;
#pragma unroll
                for (int half = 0; half < 2; half++) {
                    int chunk = half * 8 + c8;
                    bf16x8 vv = *(const bf16x8*)(vl + d * 272 + chunk * 16);
                    *(bf16x8*)(dst + chunk * 8) = vv;
                }
            }
            return;
        }
    }

    // ---- normal epilogue: LDS bounce -> dwordx4 coalesced stores
    constexpr int RS = BN * 2 + 8;   // bounce row stride (bytes)
    constexpr int CH = BN / 8;       // 16B chunks per row
    char* ep = smem;
#pragma unroll
    for (int cg = 0; cg < CG; cg++) {
        int lcol = wn * (BN / 2) + cg * 16 + l15;
        float bz = bias[n0 + lcol];
#pragma unroll
        for (int rg = 0; rg < 4; rg++) {
#pragma unroll
            for (int j = 0; j < 4; j++) {
                int lrow = wm * 64 + rg * 16 + lg * 4 + j;
                float v = acc[rg][cg][j] + bz;
                if (MODE == 1) v = fmaxf(v, 0.f);
                *(bf16*)(ep + lrow * RS + lcol * 2) = (bf16)v;
            }
        }
    }
    __syncthreads();
    int cch = tid & (CH - 1);
    int rof = tid / CH;
    constexpr int RPP = 256 / CH;    // rows per pass
#pragma unroll
    for (int i = 0; i < 128 / RPP; i++) {
        int row = i * RPP + rof;
        bf16x8 vv = *(const bf16x8*)(ep + row * RS + cch * 16);
        *(bf16x8*)(outb + (size_t)(m0 + row) * N + n0 + cch * 8) = vv;
    }
}

// ---------------------------------------------------------------
// Flash attention v8: rotated pipeline {stage(t+2) | QK(t+1) | softmax(t) |
// PV(t)} over a 3-buffer LDS ring (48KB). exp(t) is a full barrier away from
// QK(t) -> MFMA latency hidden under softmax VALU; zero-C MFMA births the
// S regs (no per-iter zero-init). No online max (regime-safe, see r7).
__global__ __launch_bounds__(256, 3)
void k_attn(const bf16* __restrict__ qkvb, const bf16* __restrict__ vt,
            bf16* __restrict__ attno) {
    __shared__ char sL[49152];       // 3 bufs x {K 8KB | V 8KB}
    const float sc = 0.044194173824159216f * 1.4426950408889634f; // 1/sqrt(512)*log2e
    int bid = blockIdx.x;
    int nb = (bid & 7) * 128 + (bid >> 3);    // XCD swizzle: 2 bh per XCD
    int bh = nb >> 6, qt = nb & 63;
    int b = bh >> 3, hh = bh & 7;
    int q0 = qt * 64;
    int tid = threadIdx.x, w = tid >> 6, l = tid & 63;
    int l15 = l & 15, lg = l >> 4, l7 = l15 & 7;
    int lg4 = lg * 4;
    int vperm = ((lg & 1) << 1) | (lg >> 1);
    const bf16* qbase = qkvb + (size_t)b * 4096 * 1536 + hh * 64;
    const bf16* kbase = qbase + 512;
    const bf16* vbase = vt + (size_t)bh * 64 * 4096;
    int srow = tid >> 3, sphys = tid & 7;

    const char* kp0 = sL + l15 * 128 + ((lg ^ l7) << 4);
    const char* kp1 = sL + l15 * 128 + (((4 + lg) ^ l7) << 4);
    const char* vp0 = sL + 8192 + l15 * 128 + ((vperm ^ l7) << 4);
    const char* vp1 = sL + 8192 + l15 * 128 + (((4 + vperm) ^ l7) << 4);
    char* dK = sL + tid * 16;
    char* dV = sL + 8192 + tid * 16;
    const char* kg = (const char*)(kbase + srow * 1536 + (sphys ^ (srow & 7)) * 8);
    const char* vg = (const char*)(vbase + srow * 4096 + (sphys ^ (srow & 7)) * 8);

    // Q fragments first (keeps vmcnt accounting pure for staging)
    bf16x8 qf[2];
#pragma unroll
    for (int ks = 0; ks < 2; ks++) {
        bf16x8 v = *(const bf16x8*)(qbase +
            (size_t)(q0 + w * 16 + l15) * 1536 + ks * 32 + lg * 8);
        bf16x8 o;
#pragma unroll
        for (int j = 0; j < 8; j++) o[j] = (bf16)((float)v[j] * sc);
        qf[ks] = o;
    }
    asm volatile("s_waitcnt vmcnt(0)" ::: "memory");

#define STG(BS)                                                               \
    do {                                                                      \
        gload16(kg, dK + (BS) * 16384);                                       \
        gload16(kg + 98304, dK + (BS) * 16384 + 4096);                        \
        gload16(vg, dV + (BS) * 16384);                                       \
        gload16(vg + 262144, dV + (BS) * 16384 + 4096);                       \
        kg += 196608;                                                         \
        vg += 128;                                                            \
    } while (0)

    STG(0);
    STG(1);

    const f32x4 kZ = {0.f, 0.f, 0.f, 0.f};
    f32x4 sE[4], sO[4];
    float lsum = 0.f;
    f32x4 acc[4];
#pragma unroll
    for (int df = 0; df < 4; df++) acc[df] = (f32x4){0.f, 0.f, 0.f, 0.f};

#define QKC(SN, BQ)                                                           \
    __builtin_amdgcn_s_setprio(1);                                            \
    SN[0] = mfma16(*(const bf16x8*)(kp0 + (BQ) * 16384 + 0 * 2048), qf[0], kZ); \
    SN[1] = mfma16(*(const bf16x8*)(kp0 + (BQ) * 16384 + 1 * 2048), qf[0], kZ); \
    SN[2] = mfma16(*(const bf16x8*)(kp0 + (BQ) * 16384 + 2 * 2048), qf[0], kZ); \
    SN[3] = mfma16(*(const bf16x8*)(kp0 + (BQ) * 16384 + 3 * 2048), qf[0], kZ); \
    SN[0] = mfma16(*(const bf16x8*)(kp1 + (BQ) * 16384 + 0 * 2048), qf[1], SN[0]); \
    SN[1] = mfma16(*(const bf16x8*)(kp1 + (BQ) * 16384 + 1 * 2048), qf[1], SN[1]); \
    SN[2] = mfma16(*(const bf16x8*)(kp1 + (BQ) * 16384 + 2 * 2048), qf[1], SN[2]); \
    SN[3] = mfma16(*(const bf16x8*)(kp1 + (BQ) * 16384 + 3 * 2048), qf[1], SN[3]); \
    __builtin_amdgcn_s_setprio(0);

#define SOFTPV(SOld, BP)                                                      \
    {                                                                         \
        float e0 = rexp2(SOld[0][0]), e1 = rexp2(SOld[0][1]);                 \
        float e2 = rexp2(SOld[0][2]), e3 = rexp2(SOld[0][3]);                 \
        float e4 = rexp2(SOld[1][0]), e5 = rexp2(SOld[1][1]);                 \
        float e6 = rexp2(SOld[1][2]), e7 = rexp2(SOld[1][3]);                 \
        float e8 = rexp2(SOld[2][0]), e9 = rexp2(SOld[2][1]);                 \
        float e10 = rexp2(SOld[2][2]), e11 = rexp2(SOld[2][3]);               \
        float e12 = rexp2(SOld[3][0]), e13 = rexp2(SOld[3][1]);               \
        float e14 = rexp2(SOld[3][2]), e15 = rexp2(SOld[3][3]);               \
        lsum += (((e0 + e1) + (e2 + e3)) + ((e4 + e5) + (e6 + e7))) +         \
                (((e8 + e9) + (e10 + e11)) + ((e12 + e13) + (e14 + e15)));    \
        int p0 = cvtpk(e0, e1), p1 = cvtpk(e2, e3);                           \
        int p2 = cvtpk(e4, e5), p3 = cvtpk(e6, e7);                           \
        int p4 = cvtpk(e8, e9), p5 = cvtpk(e10, e11);                         \
        int p6 = cvtpk(e12, e13), p7 = cvtpk(e14, e15);                       \
        asm("v_permlane16_swap_b32 %0, %1" : "+v"(p2), "+v"(p0));             \
        asm("v_permlane16_swap_b32 %0, %1" : "+v"(p3), "+v"(p1));             \
        asm("v_permlane16_swap_b32 %0, %1" : "+v"(p6), "+v"(p4));             \
        asm("v_permlane16_swap_b32 %0, %1" : "+v"(p7), "+v"(p5));             \
        {                                                                     \
            int4v ai = {p0, p1, p2, p3};                                      \
            bf16x8 af = __builtin_bit_cast(bf16x8, ai);                       \
            __builtin_amdgcn_s_setprio(1);                                    \
            acc[0] = mfma16(af, *(const bf16x8*)(vp0 + (BP) * 16384 + 0 * 2048), acc[0]); \
            acc[1] = mfma16(af, *(const bf16x8*)(vp0 + (BP) * 16384 + 1 * 2048), acc[1]); \
            acc[2] = mfma16(af, *(const bf16x8*)(vp0 + (BP) * 16384 + 2 * 2048), acc[2]); \
            acc[3] = mfma16(af, *(const bf16x8*)(vp0 + (BP) * 16384 + 3 * 2048), acc[3]); \
        }                                                                     \
        {                                                                     \
            int4v ai = {p4, p5, p6, p7};                                      \
            bf16x8 af = __builtin_bit_cast(bf16x8, ai);                       \
            acc[0] = mfma16(af, *(const bf16x8*)(vp1 + (BP) * 16384 + 0 * 2048), acc[0]); \
            acc[1] = mfma16(af, *(const bf16x8*)(vp1 + (BP) * 16384 + 1 * 2048), acc[1]); \
            acc[2] = mfma16(af, *(const bf16x8*)(vp1 + (BP) * 16384 + 2 * 2048), acc[2]); \
            acc[3] = mfma16(af, *(const bf16x8*)(vp1 + (BP) * 16384 + 3 * 2048), acc[3]); \
            __builtin_amdgcn_s_setprio(0);                                    \
        }                                                                     \
    }

#define BODY(BS, BQ, SN, SOld, BP, PF)                                        \
    {                                                                         \
        if (PF) {                                                             \
            STG(BS);                                                          \
            asm volatile("s_waitcnt vmcnt(4)" ::: "memory");                  \
        } else {                                                              \
            asm volatile("s_waitcnt vmcnt(0)" ::: "memory");                  \
        }                                                                     \
        __builtin_amdgcn_s_barrier();                                         \
        __builtin_amdgcn_sched_barrier(0);                                    \
        QKC(SN, BQ)                                                           \
        SOFTPV(SOld, BP)                                                      \
        __builtin_amdgcn_s_barrier();                                         \
    }

    // Prologue: QK(0) on buf0 (stage(0) complete after vmcnt(4))
    asm volatile("s_waitcnt vmcnt(4)" ::: "memory");
    __builtin_amdgcn_s_barrier();
    __builtin_amdgcn_sched_barrier(0);
    QKC(sE, 0)

    // Bodies t = 0..59 (pattern period 6: bufs (t+2,t+1,t)%3, parity of S)
    for (int tt = 0; tt < 10; tt++) {
        BODY(2, 1, sO, sE, 0, 1)
        BODY(0, 2, sE, sO, 1, 1)
        BODY(1, 0, sO, sE, 2, 1)
        BODY(2, 1, sE, sO, 0, 1)
        BODY(0, 2, sO, sE, 1, 1)
        BODY(1, 0, sE, sO, 2, 1)
    }
    BODY(2, 1, sO, sE, 0, 1)   // t=60
    BODY(0, 2, sE, sO, 1, 1)   // t=61
    BODY(1, 0, sO, sE, 2, 0)   // t=62 (no prefetch; drain)
    SOFTPV(sO, 0)              // t=63 tail
#undef BODY
#undef SOFTPV
#undef QKC
#undef STG

    // lsum: reduce across lg groups (q = l15), then per-acc-row inverses
    lsum += __shfl_xor(lsum, 16);
    lsum += __shfl_xor(lsum, 32);
    float invq[4];
#pragma unroll
    for (int j = 0; j < 4; j++)
        invq[j] = 1.0f / __shfl(lsum, lg4 + j);

    __syncthreads();
    bf16* ow = (bf16*)sL + w * 16 * 64;
#pragma unroll
    for (int df = 0; df < 4; df++) {
        int chunk = df * 2 + (l15 >> 3);
        int within = l15 & 7;
#pragma unroll
        for (int j = 0; j < 4; j++) {
            int q = lg * 4 + j;
            *(bf16*)((char*)ow + q * 128 + ((chunk ^ (q & 7)) << 4) + within * 2) =
                (bf16)(acc[df][j] * invq[j]);
        }
    }
    __syncthreads();
    const char* owr = (const char*)ow;
#pragma unroll
    for (int half = 0; half < 2; half++) {
        int r = l >> 2, ch = (l & 3) + half * 4;
        bf16x8 vv = *(const bf16x8*)(owr + r * 128 + ((ch ^ (r & 7)) << 4));
        *(bf16x8*)(attno + (size_t)(b * 4096 + q0 + w * 16 + r) * 512 +
                   hh * 64 + ch * 8) = vv;
    }
}

// ---------------------------------------------------------------
extern "C" void kernel_launch(void* const* d_in, const int* in_sizes, int n_in,
                              void* d_out, int out_size, void* d_ws, size_t ws_size,
                              hipStream_t stream) {
    const float* x = (const float*)d_in[0];
    const float* ln1g = (const float*)d_in[1];
    const float* ln1b = (const float*)d_in[2];
    const float* wqkv = (const float*)d_in[3];
    const float* bqkv = (const float*)d_in[4];
    const float* wproj = (const float*)d_in[5];
    const float* bproj = (const float*)d_in[6];
    const float* ln2g = (const float*)d_in[7];
    const float* ln2b = (const float*)d_in[8];
    const float* wffn1 = (const float*)d_in[9];
    const float* bffn1 = (const float*)d_in[10];
    const float* wffn2 = (const float*)d_in[11];
    const float* bffn2 = (const float*)d_in[12];
    float* y = (float*)d_out;

    char* ws = (char*)d_ws;
    float* t    = (float*)(ws + 0);           // 16M fp32, residual stream (in-place)
    bf16* h     = (bf16*)(ws + 16777216);     // h1 / attno / h2 / f2o (sequential)
    bf16* qkvb  = (bf16*)(ws + 25165824);     // 24M; f1 aliases 24M..56M
    bf16* vtb   = (bf16*)(ws + 50331648);     // 8M; po aliases (dead after attn)
    bf16* f1    = (bf16*)(ws + 25165824);
    bf16* wqT   = (bf16*)(ws + 58720256);
    bf16* wpT   = (bf16*)(ws + 60293120);
    bf16* w1T   = (bf16*)(ws + 60817408);
    bf16* w2T   = (bf16*)(ws + 62914560);
    bf16* attno = h;
    bf16* po    = vtb;
    bf16* f2o   = h;

    k_transpose_x<<<4096, 256, 0, stream>>>(x, t);
    k_ln<<<2048, 256, 0, stream>>>(t, ln1g, ln1b, h);
    k_wt<<<(512 / 32) * (1536 / 32), 256, 0, stream>>>(wqkv, wqT, 512, 1536);
    k_wt<<<(512 / 32) * (512 / 32), 256, 0, stream>>>(wproj, wpT, 512, 512);
    k_wt<<<(512 / 32) * (2048 / 32), 256, 0, stream>>>(wffn1, w1T, 512, 2048);
    k_wt<<<(2048 / 32) * (512 / 32), 256, 0, stream>>>(wffn2, w2T, 2048, 512);

    k_gemm<2, 128><<<768, 256, 0, stream>>>(h, wqT, bqkv, qkvb, vtb, 8192, 1536, 512);
    k_attn<<<1024, 256, 0, stream>>>(qkvb, vtb, attno);
    k_gemm<0, 64><<<512, 256, 0, stream>>>(attno, wpT, bproj, po, nullptr, 8192, 512, 512);
    k_lnr<<<2048, 256, 0, stream>>>(t, po, ln2g, ln2b, h);
    k_gemm<1, 128><<<1024, 256, 0, stream>>>(h, w1T, bffn1, f1, nullptr, 8192, 2048, 512);
    k_gemm<0, 64><<<512, 256, 0, stream>>>(f1, w2T, bffn2, f2o, nullptr, 8192, 512, 2048);
    k_out3<<<4096, 256, 0, stream>>>(t, f2o, x, y);
}

// Round 9
// 201.211 us; speedup vs baseline: 1.0352x; 1.0352x over previous
//
#include <hip/hip_runtime.h>
#include <hip/hip_bf16.h>

typedef __bf16 bf16;
typedef __bf16 bf16x8 __attribute__((ext_vector_type(8)));
typedef __bf16 bf16x4 __attribute__((ext_vector_type(4)));
typedef float f32x4 __attribute__((ext_vector_type(4)));
typedef int int4v __attribute__((ext_vector_type(4)));
typedef int int2v __attribute__((ext_vector_type(2)));

#define DEV static __device__ __forceinline__

DEV void gload16(const void* g, void* l) {
    __builtin_amdgcn_global_load_lds(
        (const __attribute__((address_space(1))) void*)g,
        (__attribute__((address_space(3))) void*)l, 16, 0, 0);
}

DEV f32x4 mfma16(bf16x8 a, bf16x8 b, f32x4 c) {
    return __builtin_amdgcn_mfma_f32_16x16x32_bf16(a, b, c, 0, 0, 0);
}

DEV int cvtpk(float lo, float hi) {
    int r;
    asm("v_cvt_pk_bf16_f32 %0, %1, %2" : "=v"(r) : "v"(lo), "v"(hi));
    return r;
}

DEV float rexp2(float x) {   // raw v_exp_f32 (no denormal guard)
    float r;
    asm("v_exp_f32 %0, %1" : "=v"(r) : "v"(x));
    return r;
}

// ---------------------------------------------------------------
// x [B][512][4096] -> t [B*4096][512] (fp32), tiled transpose
__global__ __launch_bounds__(256)
void k_transpose_x(const float* __restrict__ x, float* __restrict__ t) {
    __shared__ float tile[32][33];
    int bid = blockIdx.x;
    int nt = bid & 127, ct = (bid >> 7) & 15, b = bid >> 11;
    int n0 = nt * 32, c0 = ct * 32;
    int tid = threadIdx.x;
    const float* xb = x + (size_t)b * 512 * 4096;
    int nl = tid & 31, cl = tid >> 5;
#pragma unroll
    for (int i = 0; i < 4; i++) {
        int c = cl + i * 8;
        tile[c][nl] = xb[(size_t)(c0 + c) * 4096 + n0 + nl];
    }
    __syncthreads();
    float* tb = t + (size_t)b * 4096 * 512;
    int cl2 = tid & 31, nl2 = tid >> 5;
#pragma unroll
    for (int i = 0; i < 4; i++) {
        int n = nl2 + i * 8;
        tb[(size_t)(n0 + n) * 512 + c0 + cl2] = tile[cl2][n];
    }
}

// ---------------------------------------------------------------
// y [B][512][4096] = transpose(t + f2o) + x   (final residual fused)
__global__ __launch_bounds__(256)
void k_out3(const float* __restrict__ t, const bf16* __restrict__ f2o,
            const float* __restrict__ x, float* __restrict__ y) {
    __shared__ float tile[32][33];
    int bid = blockIdx.x;
    int nt = bid & 127, ct = (bid >> 7) & 15, b = bid >> 11;
    int n0 = nt * 32, c0 = ct * 32;
    int tid = threadIdx.x;
#pragma unroll
    for (int i = 0; i < 4; i++) {
        int nl = (tid >> 5) + i * 8;
        size_t idx = (size_t)(b * 4096 + n0 + nl) * 512 + c0 + (tid & 31);
        tile[tid & 31][nl] = t[idx] + (float)f2o[idx];
    }
    __syncthreads();
    const float* xb = x + ((size_t)b * 512 + c0) * 4096;
    float* yb = y + ((size_t)b * 512 + c0) * 4096;
#pragma unroll
    for (int i = 0; i < 4; i++) {
        int cl = (tid >> 5) + i * 8;
        int nl = tid & 31;
        size_t off = (size_t)cl * 4096 + n0 + nl;
        yb[off] = tile[cl][nl] + xb[off];
    }
}

// ---------------------------------------------------------------
// LayerNorm: t fp32 -> h bf16. One wave per row.
__global__ __launch_bounds__(256)
void k_ln(const float* __restrict__ t, const float* __restrict__ gg,
          const float* __restrict__ bb, bf16* __restrict__ h) {
    int lane = threadIdx.x & 63;
    int row = blockIdx.x * 4 + (threadIdx.x >> 6);
    const float* tr = t + (size_t)row * 512;
    f32x4 v0 = *(const f32x4*)(tr + lane * 4);
    f32x4 v1 = *(const f32x4*)(tr + 256 + lane * 4);
    float s = v0[0] + v0[1] + v0[2] + v0[3] + v1[0] + v1[1] + v1[2] + v1[3];
#pragma unroll
    for (int m = 1; m < 64; m <<= 1) s += __shfl_xor(s, m);
    float mu = s * (1.0f / 512.0f);
    float vs = 0.f;
#pragma unroll
    for (int j = 0; j < 4; j++) {
        float d0 = v0[j] - mu, d1 = v1[j] - mu;
        vs += d0 * d0 + d1 * d1;
    }
#pragma unroll
    for (int m = 1; m < 64; m <<= 1) vs += __shfl_xor(vs, m);
    float rs = rsqrtf(vs * (1.0f / 512.0f) + 1e-5f);
    f32x4 g0 = *(const f32x4*)(gg + lane * 4);
    f32x4 g1 = *(const f32x4*)(gg + 256 + lane * 4);
    f32x4 b0 = *(const f32x4*)(bb + lane * 4);
    f32x4 b1 = *(const f32x4*)(bb + 256 + lane * 4);
    bf16x4 o0, o1;
#pragma unroll
    for (int j = 0; j < 4; j++) {
        o0[j] = (bf16)((v0[j] - mu) * rs * g0[j] + b0[j]);
        o1[j] = (bf16)((v1[j] - mu) * rs * g1[j] + b1[j]);
    }
    *(bf16x4*)(h + (size_t)row * 512 + lane * 4) = o0;
    *(bf16x4*)(h + (size_t)row * 512 + 256 + lane * 4) = o1;
}

// ---------------------------------------------------------------
// Fused residual + LayerNorm: t = t + r(bf16); h = LN(t). In-place t.
__global__ __launch_bounds__(256)
void k_lnr(float* __restrict__ t, const bf16* __restrict__ r,
           const float* __restrict__ gg, const float* __restrict__ bb,
           bf16* __restrict__ h) {
    int lane = threadIdx.x & 63;
    int row = blockIdx.x * 4 + (threadIdx.x >> 6);
    float* tr = t + (size_t)row * 512;
    f32x4 v0 = *(const f32x4*)(tr + lane * 4);
    f32x4 v1 = *(const f32x4*)(tr + 256 + lane * 4);
    bf16x4 r0 = *(const bf16x4*)(r + (size_t)row * 512 + lane * 4);
    bf16x4 r1 = *(const bf16x4*)(r + (size_t)row * 512 + 256 + lane * 4);
#pragma unroll
    for (int j = 0; j < 4; j++) {
        v0[j] += (float)r0[j];
        v1[j] += (float)r1[j];
    }
    *(f32x4*)(tr + lane * 4) = v0;
    *(f32x4*)(tr + 256 + lane * 4) = v1;
    float s = v0[0] + v0[1] + v0[2] + v0[3] + v1[0] + v1[1] + v1[2] + v1[3];
#pragma unroll
    for (int m = 1; m < 64; m <<= 1) s += __shfl_xor(s, m);
    float mu = s * (1.0f / 512.0f);
    float vs = 0.f;
#pragma unroll
    for (int j = 0; j < 4; j++) {
        float d0 = v0[j] - mu, d1 = v1[j] - mu;
        vs += d0 * d0 + d1 * d1;
    }
#pragma unroll
    for (int m = 1; m < 64; m <<= 1) vs += __shfl_xor(vs, m);
    float rs = rsqrtf(vs * (1.0f / 512.0f) + 1e-5f);
    f32x4 g0 = *(const f32x4*)(gg + lane * 4);
    f32x4 g1 = *(const f32x4*)(gg + 256 + lane * 4);
    f32x4 b0 = *(const f32x4*)(bb + lane * 4);
    f32x4 b1 = *(const f32x4*)(bb + 256 + lane * 4);
    bf16x4 o0, o1;
#pragma unroll
    for (int j = 0; j < 4; j++) {
        o0[j] = (bf16)((v0[j] - mu) * rs * g0[j] + b0[j]);
        o1[j] = (bf16)((v1[j] - mu) * rs * g1[j] + b1[j]);
    }
    *(bf16x4*)(h + (size_t)row * 512 + lane * 4) = o0;
    *(bf16x4*)(h + (size_t)row * 512 + 256 + lane * 4) = o1;
}

// ---------------------------------------------------------------
// Weight prep: W [K][N] fp32 -> WT [N][K] bf16
__global__ __launch_bounds__(256)
void k_wt(const float* __restrict__ w, bf16* __restrict__ wt, int K, int N) {
    __shared__ float tile[32][33];
    int ntn = N >> 5;
    int kt = blockIdx.x / ntn, ntile = blockIdx.x % ntn;
    int k0 = kt * 32, n0 = ntile * 32;
    int tid = threadIdx.x;
    int nl = tid & 31, kl = tid >> 5;
#pragma unroll
    for (int i = 0; i < 4; i++) {
        int k = kl + i * 8;
        tile[k][nl] = w[(size_t)(k0 + k) * N + n0 + nl];
    }
    __syncthreads();
    int kl2 = tid & 31, nl2 = tid >> 5;
#pragma unroll
    for (int i = 0; i < 4; i++) {
        int n = nl2 + i * 8;
        wt[(size_t)(n0 + n) * K + k0 + kl2] = (bf16)tile[kl2][n];
    }
}

// ---------------------------------------------------------------
// GEMM: out[M][N](bf16) = A[M][K](bf16) @ BT[N][K]^T + bias.
// MODE 0 plain / 1 relu / 2 qkv (V-slice transposed into vt);
// BN = 128 or 64. LDS right-sized: 32768 + 2*CG*4096 (48KB at BN=64 ->
// 3 blocks/CU). Counted-vmcnt 2-barrier pipeline; LDS-bounce epilogue.
template <int MODE, int BN>
__global__ __launch_bounds__(256, BN == 64 ? 3 : 2)
void k_gemm(const bf16* __restrict__ A, const bf16* __restrict__ BT,
            const float* __restrict__ bias, bf16* __restrict__ outb,
            bf16* __restrict__ vtout, int M, int N, int K) {
    constexpr int CG = BN / 32;          // col-groups per wave / B stage passes
    constexpr int BSZ = CG * 4096;       // one B buffer, bytes
    __shared__ char smem[32768 + 2 * BSZ];
    int ntn = N / BN;
    int nwg = gridDim.x;
    int bid = blockIdx.x;
    int cpx = nwg >> 3;
    bid = (bid & 7) * cpx + (bid >> 3);       // XCD-aware swizzle
    int bm = bid / ntn, bn = bid % ntn;
    int m0 = bm * 128, n0 = bn * BN;
    int tid = threadIdx.x;
    int w = tid >> 6, l = tid & 63;
    int wm = w >> 1, wn = w & 1;
    int l15 = l & 15, lg = l >> 4;

    f32x4 acc[4][CG];
#pragma unroll
    for (int i = 0; i < 4; i++)
#pragma unroll
        for (int j = 0; j < CG; j++) acc[i][j] = (f32x4){0.f, 0.f, 0.f, 0.f};

    int srow = tid >> 3, sphys = tid & 7;
    int lrow_a = wm * 64 + l15;
    int lrow_b = wn * (BN / 2) + l15;

#define GEMM_STAGE(k0v, bb)                                                  \
    do {                                                                     \
        _Pragma("unroll") for (int s = 0; s < 4; s++) {                      \
            int row = s * 32 + srow;                                         \
            int k16 = sphys ^ (row & 7);                                     \
            gload16(A + (size_t)(m0 + row) * K + (k0v) + k16 * 8,            \
                    smem + (bb) * 16384 + s * 4096 + tid * 16);              \
        }                                                                    \
        _Pragma("unroll") for (int s = 0; s < CG; s++) {                     \
            int row = s * 32 + srow;                                         \
            int k16 = sphys ^ (row & 7);                                     \
            gload16(BT + (size_t)(n0 + row) * K + (k0v) + k16 * 8,           \
                    smem + 32768 + (bb) * BSZ + s * 4096 + tid * 16);        \
        }                                                                    \
    } while (0)

    int nk = K >> 6;
    GEMM_STAGE(0, 0);
    int cur = 0;
    for (int kt = 0; kt < nk; kt++) {
        if (kt + 1 < nk) {
            GEMM_STAGE((kt + 1) << 6, cur ^ 1);
            if constexpr (BN == 128)
                asm volatile("s_waitcnt vmcnt(8)" ::: "memory");
            else
                asm volatile("s_waitcnt vmcnt(6)" ::: "memory");
        } else {
            asm volatile("s_waitcnt vmcnt(0)" ::: "memory");
        }
        __builtin_amdgcn_s_barrier();
        __builtin_amdgcn_sched_barrier(0);
        const char* pA = smem + cur * 16384;
        const char* pB = smem + 32768 + cur * BSZ;
#pragma unroll
        for (int ks = 0; ks < 2; ks++) {
            bf16x8 af[4], bfr[CG];
#pragma unroll
            for (int rg = 0; rg < 4; rg++) {
                int row = lrow_a + rg * 16;
                af[rg] = *(const bf16x8*)(pA + row * 128 +
                                          (((lg + ks * 4) ^ (row & 7)) << 4));
            }
#pragma unroll
            for (int cg = 0; cg < CG; cg++) {
                int row = lrow_b + cg * 16;
                bfr[cg] = *(const bf16x8*)(pB + row * 128 +
                                           (((lg + ks * 4) ^ (row & 7)) << 4));
            }
#pragma unroll
            for (int rg = 0; rg < 4; rg++)
#pragma unroll
                for (int cg = 0; cg < CG; cg++)
                    acc[rg][cg] = mfma16(af[rg], bfr[cg], acc[rg][cg]);
        }
        __builtin_amdgcn_s_barrier();
        cur ^= 1;
    }
#undef GEMM_STAGE

    if constexpr (MODE == 2) {
        if (n0 >= 1024) {
            // ---- V-slice: transposed epilogue into vt [bh][64][4096]
            char* vl = smem;        // col-major [128 col][136 row] bf16
#pragma unroll
            for (int cg = 0; cg < CG; cg++) {
                int col = wn * 64 + cg * 16 + l15;
                float bz = bias[n0 + col];
#pragma unroll
                for (int rg = 0; rg < 4; rg++) {
                    int rowb = wm * 64 + rg * 16 + lg * 4;
                    int2v qq = {cvtpk(acc[rg][cg][0] + bz, acc[rg][cg][1] + bz),
                                cvtpk(acc[rg][cg][2] + bz, acc[rg][cg][3] + bz)};
                    *(int2v*)(vl + col * 272 + rowb * 2) = qq;
                }
            }
            __syncthreads();
            int b = m0 >> 12, nrow0 = m0 & 4095;
            int dl = tid >> 3, c8 = tid & 7;
#pragma unroll
            for (int dd = 0; dd < 4; dd++) {
                int d = dd * 32 + dl;
                int ch = (n0 - 1024) + d;
                bf16* dst = vtout +
                    ((size_t)((b * 8 + (ch >> 6)) * 64 + (ch & 63))) * 4096 + nrow0;
#pragma unroll
                for (int half = 0; half < 2; half++) {
                    int chunk = half * 8 + c8;
                    bf16x8 vv = *(const bf16x8*)(vl + d * 272 + chunk * 16);
                    *(bf16x8*)(dst + chunk * 8) = vv;
                }
            }
            return;
        }
    }

    // ---- normal epilogue: LDS bounce -> dwordx4 coalesced stores
    constexpr int RS = BN * 2 + 8;   // bounce row stride (bytes)
    constexpr int CH = BN / 8;       // 16B chunks per row
    char* ep = smem;
#pragma unroll
    for (int cg = 0; cg < CG; cg++) {
        int lcol = wn * (BN / 2) + cg * 16 + l15;
        float bz = bias[n0 + lcol];
#pragma unroll
        for (int rg = 0; rg < 4; rg++) {
#pragma unroll
            for (int j = 0; j < 4; j++) {
                int lrow = wm * 64 + rg * 16 + lg * 4 + j;
                float v = acc[rg][cg][j] + bz;
                if (MODE == 1) v = fmaxf(v, 0.f);
                *(bf16*)(ep + lrow * RS + lcol * 2) = (bf16)v;
            }
        }
    }
    __syncthreads();
    int cch = tid & (CH - 1);
    int rof = tid / CH;
    constexpr int RPP = 256 / CH;    // rows per pass
#pragma unroll
    for (int i = 0; i < 128 / RPP; i++) {
        int row = i * RPP + rof;
        bf16x8 vv = *(const bf16x8*)(ep + row * RS + cch * 16);
        *(bf16x8*)(outb + (size_t)(m0 + row) * N + n0 + cch * 8) = vv;
    }
}

// ---------------------------------------------------------------
// Flash attention v9: v7 structure (2-buf dbuf, counted vmcnt, 2 barriers,
// 32KB LDS -> 4 blocks/CU) + intra-phase interleave: QK(s0,s1) -> exp(e0-7)
// -> QK(s2,s3) -> PV(af0) -> exp(e8-15) -> PV(af1). Same accumulation order
// as v7 (numerically identical); exp chains overlap MFMA clusters.
__global__ __launch_bounds__(256, 4)
void k_attn(const bf16* __restrict__ qkvb, const bf16* __restrict__ vt,
            bf16* __restrict__ attno) {
    __shared__ bf16 sK[2][64 * 64];
    __shared__ bf16 sV[2][64 * 64];
    const float sc = 0.044194173824159216f * 1.4426950408889634f; // 1/sqrt(512)*log2e
    int bid = blockIdx.x;
    int nb = (bid & 7) * 128 + (bid >> 3);    // XCD swizzle: 2 bh per XCD
    int bh = nb >> 6, qt = nb & 63;
    int b = bh >> 3, hh = bh & 7;
    int q0 = qt * 64;
    int tid = threadIdx.x, w = tid >> 6, l = tid & 63;
    int l15 = l & 15, lg = l >> 4, l7 = l15 & 7;
    int lg4 = lg * 4;
    int vperm = ((lg & 1) << 1) | (lg >> 1);
    const bf16* qbase = qkvb + (size_t)b * 4096 * 1536 + hh * 64;
    const bf16* kbase = qbase + 512;
    const bf16* vbase = vt + (size_t)bh * 64 * 4096;
    int srow = tid >> 3, sphys = tid & 7;

    const char* kp0 = (const char*)&sK[0][0] + l15 * 128 + ((lg ^ l7) << 4);
    const char* kp1 = (const char*)&sK[0][0] + l15 * 128 + (((4 + lg) ^ l7) << 4);
    const char* vp0 = (const char*)&sV[0][0] + l15 * 128 + ((vperm ^ l7) << 4);
    const char* vp1 = (const char*)&sV[0][0] + l15 * 128 + (((4 + vperm) ^ l7) << 4);
    char* dK0 = (char*)&sK[0][0] + tid * 16;
    char* dV0 = (char*)&sV[0][0] + tid * 16;
    const char* kg = (const char*)(kbase + srow * 1536 + (sphys ^ (srow & 7)) * 8);
    const char* vg = (const char*)(vbase + srow * 4096 + (sphys ^ (srow & 7)) * 8);

    gload16(kg, dK0);
    gload16(kg + 98304, dK0 + 4096);
    gload16(vg, dV0);
    gload16(vg + 262144, dV0 + 4096);
    kg += 196608;
    vg += 128;

    bf16x8 qf[2];
#pragma unroll
    for (int ks = 0; ks < 2; ks++) {
        bf16x8 v = *(const bf16x8*)(qbase +
            (size_t)(q0 + w * 16 + l15) * 1536 + ks * 32 + lg * 8);
        bf16x8 o;
#pragma unroll
        for (int j = 0; j < 8; j++) o[j] = (bf16)((float)v[j] * sc);
        qf[ks] = o;
    }

    const f32x4 kZ = {0.f, 0.f, 0.f, 0.f};
    float lsum = 0.f;
    f32x4 acc[4];
#pragma unroll
    for (int df = 0; df < 4; df++) acc[df] = kZ;

#define ABODY(BUF, PF)                                                        \
    {                                                                         \
        if (PF) {                                                             \
            gload16(kg, dK0 + (1 - (BUF)) * 8192);                            \
            gload16(kg + 98304, dK0 + (1 - (BUF)) * 8192 + 4096);             \
            gload16(vg, dV0 + (1 - (BUF)) * 8192);                            \
            gload16(vg + 262144, dV0 + (1 - (BUF)) * 8192 + 4096);            \
            kg += 196608;                                                     \
            vg += 128;                                                        \
            asm volatile("s_waitcnt vmcnt(4)" ::: "memory");                  \
        } else {                                                              \
            asm volatile("s_waitcnt vmcnt(0)" ::: "memory");                  \
        }                                                                     \
        __builtin_amdgcn_s_barrier();                                         \
        __builtin_amdgcn_sched_barrier(0);                                    \
        f32x4 s0, s1, s2, s3;                                                 \
        __builtin_amdgcn_s_setprio(1);                                        \
        s0 = mfma16(*(const bf16x8*)(kp0 + (BUF) * 8192 + 0 * 2048), qf[0], kZ); \
        s0 = mfma16(*(const bf16x8*)(kp1 + (BUF) * 8192 + 0 * 2048), qf[1], s0); \
        s1 = mfma16(*(const bf16x8*)(kp0 + (BUF) * 8192 + 1 * 2048), qf[0], kZ); \
        s1 = mfma16(*(const bf16x8*)(kp1 + (BUF) * 8192 + 1 * 2048), qf[1], s1); \
        __builtin_amdgcn_s_setprio(0);                                        \
        float e0 = rexp2(s0[0]), e1 = rexp2(s0[1]);                           \
        float e2 = rexp2(s0[2]), e3 = rexp2(s0[3]);                           \
        float e4 = rexp2(s1[0]), e5 = rexp2(s1[1]);                           \
        float e6 = rexp2(s1[2]), e7 = rexp2(s1[3]);                           \
        __builtin_amdgcn_s_setprio(1);                                        \
        s2 = mfma16(*(const bf16x8*)(kp0 + (BUF) * 8192 + 2 * 2048), qf[0], kZ); \
        s2 = mfma16(*(const bf16x8*)(kp1 + (BUF) * 8192 + 2 * 2048), qf[1], s2); \
        s3 = mfma16(*(const bf16x8*)(kp0 + (BUF) * 8192 + 3 * 2048), qf[0], kZ); \
        s3 = mfma16(*(const bf16x8*)(kp1 + (BUF) * 8192 + 3 * 2048), qf[1], s3); \
        __builtin_amdgcn_s_setprio(0);                                        \
        int p0 = cvtpk(e0, e1), p1 = cvtpk(e2, e3);                           \
        int p2 = cvtpk(e4, e5), p3 = cvtpk(e6, e7);                           \
        asm("v_permlane16_swap_b32 %0, %1" : "+v"(p2), "+v"(p0));             \
        asm("v_permlane16_swap_b32 %0, %1" : "+v"(p3), "+v"(p1));             \
        {                                                                     \
            int4v ai = {p0, p1, p2, p3};                                      \
            bf16x8 af = __builtin_bit_cast(bf16x8, ai);                       \
            __builtin_amdgcn_s_setprio(1);                                    \
            acc[0] = mfma16(af, *(const bf16x8*)(vp0 + (BUF) * 8192 + 0 * 2048), acc[0]); \
            acc[1] = mfma16(af, *(const bf16x8*)(vp0 + (BUF) * 8192 + 1 * 2048), acc[1]); \
            acc[2] = mfma16(af, *(const bf16x8*)(vp0 + (BUF) * 8192 + 2 * 2048), acc[2]); \
            acc[3] = mfma16(af, *(const bf16x8*)(vp0 + (BUF) * 8192 + 3 * 2048), acc[3]); \
            __builtin_amdgcn_s_setprio(0);                                    \
        }                                                                     \
        float e8 = rexp2(s2[0]), e9 = rexp2(s2[1]);                           \
        float e10 = rexp2(s2[2]), e11 = rexp2(s2[3]);                         \
        float e12 = rexp2(s3[0]), e13 = rexp2(s3[1]);                         \
        float e14 = rexp2(s3[2]), e15 = rexp2(s3[3]);                         \
        int p4 = cvtpk(e8, e9), p5 = cvtpk(e10, e11);                         \
        int p6 = cvtpk(e12, e13), p7 = cvtpk(e14, e15);                       \
        asm("v_permlane16_swap_b32 %0, %1" : "+v"(p6), "+v"(p4));             \
        asm("v_permlane16_swap_b32 %0, %1" : "+v"(p7), "+v"(p5));             \
        {                                                                     \
            int4v ai = {p4, p5, p6, p7};                                      \
            bf16x8 af = __builtin_bit_cast(bf16x8, ai);                       \
            __builtin_amdgcn_s_setprio(1);                                    \
            acc[0] = mfma16(af, *(const bf16x8*)(vp1 + (BUF) * 8192 + 0 * 2048), acc[0]); \
            acc[1] = mfma16(af, *(const bf16x8*)(vp1 + (BUF) * 8192 + 1 * 2048), acc[1]); \
            acc[2] = mfma16(af, *(const bf16x8*)(vp1 + (BUF) * 8192 + 2 * 2048), acc[2]); \
            acc[3] = mfma16(af, *(const bf16x8*)(vp1 + (BUF) * 8192 + 3 * 2048), acc[3]); \
            __builtin_amdgcn_s_setprio(0);                                    \
        }                                                                     \
        lsum += (((e0 + e1) + (e2 + e3)) + ((e4 + e5) + (e6 + e7))) +         \
                (((e8 + e9) + (e10 + e11)) + ((e12 + e13) + (e14 + e15)));    \
        __builtin_amdgcn_s_barrier();                                         \
    }

    for (int tt = 0; tt < 31; tt++) {
        ABODY(0, 1)
        ABODY(1, 1)
    }
    ABODY(0, 1)
    ABODY(1, 0)
#undef ABODY

    // lsum: reduce across lg groups (q = l15), then per-acc-row inverses
    lsum += __shfl_xor(lsum, 16);
    lsum += __shfl_xor(lsum, 32);
    float invq[4];
#pragma unroll
    for (int j = 0; j < 4; j++)
        invq[j] = 1.0f / __shfl(lsum, lg4 + j);

    bf16* ow = (bf16*)&sK[0][0] + w * 16 * 64;
#pragma unroll
    for (int df = 0; df < 4; df++) {
        int chunk = df * 2 + (l15 >> 3);
        int within = l15 & 7;
#pragma unroll
        for (int j = 0; j < 4; j++) {
            int q = lg * 4 + j;
            *(bf16*)((char*)ow + q * 128 + ((chunk ^ (q & 7)) << 4) + within * 2) =
                (bf16)(acc[df][j] * invq[j]);
        }
    }
    __syncthreads();
    const char* owr = (const char*)ow;
#pragma unroll
    for (int half = 0; half < 2; half++) {
        int r = l >> 2, ch = (l & 3) + half * 4;
        bf16x8 vv = *(const bf16x8*)(owr + r * 128 + ((ch ^ (r & 7)) << 4));
        *(bf16x8*)(attno + (size_t)(b * 4096 + q0 + w * 16 + r) * 512 +
                   hh * 64 + ch * 8) = vv;
    }
}

// ---------------------------------------------------------------
extern "C" void kernel_launch(void* const* d_in, const int* in_sizes, int n_in,
                              void* d_out, int out_size, void* d_ws, size_t ws_size,
                              hipStream_t stream) {
    const float* x = (const float*)d_in[0];
    const float* ln1g = (const float*)d_in[1];
    const float* ln1b = (const float*)d_in[2];
    const float* wqkv = (const float*)d_in[3];
    const float* bqkv = (const float*)d_in[4];
    const float* wproj = (const float*)d_in[5];
    const float* bproj = (const float*)d_in[6];
    const float* ln2g = (const float*)d_in[7];
    const float* ln2b = (const float*)d_in[8];
    const float* wffn1 = (const float*)d_in[9];
    const float* bffn1 = (const float*)d_in[10];
    const float* wffn2 = (const float*)d_in[11];
    const float* bffn2 = (const float*)d_in[12];
    float* y = (float*)d_out;

    char* ws = (char*)d_ws;
    float* t    = (float*)(ws + 0);           // 16M fp32, residual stream (in-place)
    bf16* h     = (bf16*)(ws + 16777216);     // h1 / attno / h2 / f2o (sequential)
    bf16* qkvb  = (bf16*)(ws + 25165824);     // 24M; f1 aliases 24M..56M
    bf16* vtb   = (bf16*)(ws + 50331648);     // 8M; po aliases (dead after attn)
    bf16* f1    = (bf16*)(ws + 25165824);
    bf16* wqT   = (bf16*)(ws + 58720256);
    bf16* wpT   = (bf16*)(ws + 60293120);
    bf16* w1T   = (bf16*)(ws + 60817408);
    bf16* w2T   = (bf16*)(ws + 62914560);
    bf16* attno = h;
    bf16* po    = vtb;
    bf16* f2o   = h;

    k_transpose_x<<<4096, 256, 0, stream>>>(x, t);
    k_ln<<<2048, 256, 0, stream>>>(t, ln1g, ln1b, h);
    k_wt<<<(512 / 32) * (1536 / 32), 256, 0, stream>>>(wqkv, wqT, 512, 1536);
    k_wt<<<(512 / 32) * (512 / 32), 256, 0, stream>>>(wproj, wpT, 512, 512);
    k_wt<<<(512 / 32) * (2048 / 32), 256, 0, stream>>>(wffn1, w1T, 512, 2048);
    k_wt<<<(2048 / 32) * (512 / 32), 256, 0, stream>>>(wffn2, w2T, 2048, 512);

    k_gemm<2, 128><<<768, 256, 0, stream>>>(h, wqT, bqkv, qkvb, vtb, 8192, 1536, 512);
    k_attn<<<1024, 256, 0, stream>>>(qkvb, vtb, attno);
    k_gemm<0, 64><<<512, 256, 0, stream>>>(attno, wpT, bproj, po, nullptr, 8192, 512, 512);
    k_lnr<<<2048, 256, 0, stream>>>(t, po, ln2g, ln2b, h);
    k_gemm<1, 128><<<1024, 256, 0, stream>>>(h, w1T, bffn1, f1, nullptr, 8192, 2048, 512);
    k_gemm<0, 64><<<512, 256, 0, stream>>>(f1, w2T, bffn2, f2o, nullptr, 8192, 512, 2048);
    k_out3<<<4096, 256, 0, stream>>>(t, f2o, x, y);
}